// Round 5
// baseline (169.029 us; speedup 1.0000x reference)
//
#include <hip/hip_runtime.h>
#include <hip/hip_fp16.h>

#define POOLED 7
#define RATIO 2

constexpr int C_ = 256;
constexpr int H_ = 192;
constexpr int W_ = 192;
constexpr int P_ = H_ * W_;           // pixels per plane
constexpr int PP2 = POOLED * POOLED;  // 49

// ---------------- NCHW fp32 -> NHWC fp16 transpose -------------------------
// Tile: 32 channels x 128 pixels. Block = 256 threads.
constexpr int TC = 32;
constexpr int TP = 128;
constexpr int TPAD = TP + 1;

__global__ __launch_bounds__(256)
void nchw_to_nhwc_h(const float* __restrict__ in, __half* __restrict__ outT) {
    __shared__ float tile[TC][TPAD];
    const int b  = blockIdx.z;
    const int p0 = blockIdx.x * TP;
    const int c0 = blockIdx.y * TC;
    const float* src = in   + (size_t)b * C_ * P_;
    __half*      dst = outT + (size_t)b * P_ * C_;

    const int t = threadIdx.x;

    #pragma unroll
    for (int k = 0; k < 4; ++k) {
        const int q  = t + 256 * k;        // 0..1023
        const int c  = q >> 5;             // 0..31
        const int pv = q & 31;             // 0..31
        const float4 v = *(const float4*)&src[(size_t)(c0 + c) * P_ + p0 + 4 * pv];
        tile[c][4 * pv + 0] = v.x;
        tile[c][4 * pv + 1] = v.y;
        tile[c][4 * pv + 2] = v.z;
        tile[c][4 * pv + 3] = v.w;
    }
    __syncthreads();

    #pragma unroll
    for (int k = 0; k < 2; ++k) {
        const int q  = t + 256 * k;        // 0..511
        const int p  = q >> 2;             // 0..127
        const int c8 = (q & 3) * 8;        // 0,8,16,24
        union { __half h[8]; float4 f; } u;
        #pragma unroll
        for (int i = 0; i < 8; ++i) u.h[i] = __float2half(tile[c8 + i][p]);
        *(float4*)&dst[(size_t)(p0 + p) * C_ + c0 + c8] = u.f;
    }
}

__device__ inline float4 h4_to_f4(uint2 r) {
    const float2 a = __half22float2(*(const __half2*)&r.x);
    const float2 b = __half22float2(*(const __half2*)&r.y);
    return make_float4(a.x, a.y, b.x, b.y);
}

// ---------------- RoIAlign on NHWC fp16, fp16 bin-major LDS staging --------
// Block = 512 (8 waves). LDS 25 KB -> 4 blocks/CU (wave-capped) = 100%.
__global__ __launch_bounds__(512)
void roi_align_nhwc_h(const float* __restrict__ rois,
                      const __half* __restrict__ featT,   // (B,H,W,C) fp16
                      const int* __restrict__ stride_ptr,
                      float* __restrict__ out, int N) {
    __shared__ __half lds_out[PP2 * C_];   // bin-major: [bin][c], 25088 B

    const int n    = blockIdx.x;
    const int lane = threadIdx.x & 63;
    const int wave = threadIdx.x >> 6;     // 0..7

    const float scale = 1.0f / (float)stride_ptr[0];
    const float* r = rois + (size_t)n * 5;
    const int   b  = (int)r[0];
    const float x1 = r[1] * scale;
    const float y1 = r[2] * scale;
    const float x2 = r[3] * scale;
    const float y2 = r[4] * scale;
    const float bin_w = fmaxf(x2 - x1, 1.0f) * (1.0f / (float)POOLED);
    const float bin_h = fmaxf(y2 - y1, 1.0f) * (1.0f / (float)POOLED);

    const uint2* fbase = (const uint2*)featT + (size_t)b * P_ * (C_ / 4);
    const int cb = lane * 4;

    for (int bin = wave; bin < PP2; bin += 8) {
        const int ph = bin / POOLED;
        const int pw = bin - ph * POOLED;

        float4 acc = make_float4(0.f, 0.f, 0.f, 0.f);

        #pragma unroll
        for (int sy = 0; sy < RATIO; ++sy) {
            const float yy = y1 + ((float)(ph * RATIO + sy) + 0.5f) * (1.0f / RATIO) * bin_h;
            const bool  vy = (yy > -1.0f) && (yy < (float)H_);
            float cy = fminf(fmaxf(yy, 0.0f), (float)(H_ - 1));
            int   y0 = (int)floorf(cy);
            if (y0 > H_ - 1) y0 = H_ - 1;
            const int   y1i = min(y0 + 1, H_ - 1);
            const float fy  = cy - (float)y0;
            const float hy  = 1.0f - fy;

            #pragma unroll
            for (int sx = 0; sx < RATIO; ++sx) {
                const float xx = x1 + ((float)(pw * RATIO + sx) + 0.5f) * (1.0f / RATIO) * bin_w;
                const bool  vx = (xx > -1.0f) && (xx < (float)W_);
                if (!(vy && vx)) continue;
                float cx = fminf(fmaxf(xx, 0.0f), (float)(W_ - 1));
                int   x0 = (int)floorf(cx);
                if (x0 > W_ - 1) x0 = W_ - 1;
                const int   x1i = min(x0 + 1, W_ - 1);
                const float fx  = cx - (float)x0;
                const float hx  = 1.0f - fx;

                const float w00 = hy * hx, w01 = hy * fx, w10 = fy * hx, w11 = fy * fx;

                const float4 v00 = h4_to_f4(fbase[(size_t)(y0  * W_ + x0 ) * (C_ / 4) + lane]);
                const float4 v01 = h4_to_f4(fbase[(size_t)(y0  * W_ + x1i) * (C_ / 4) + lane]);
                const float4 v10 = h4_to_f4(fbase[(size_t)(y1i * W_ + x0 ) * (C_ / 4) + lane]);
                const float4 v11 = h4_to_f4(fbase[(size_t)(y1i * W_ + x1i) * (C_ / 4) + lane]);

                acc.x = fmaf(w00, v00.x, fmaf(w01, v01.x, fmaf(w10, v10.x, fmaf(w11, v11.x, acc.x))));
                acc.y = fmaf(w00, v00.y, fmaf(w01, v01.y, fmaf(w10, v10.y, fmaf(w11, v11.y, acc.y))));
                acc.z = fmaf(w00, v00.z, fmaf(w01, v01.z, fmaf(w10, v10.z, fmaf(w11, v11.z, acc.z))));
                acc.w = fmaf(w00, v00.w, fmaf(w01, v01.w, fmaf(w10, v10.w, fmaf(w11, v11.w, acc.w))));
            }
        }

        // Pack 4 channels -> 8 B, one conflict-free ds_write_b64.
        union { __half2 h2[2]; uint2 u; } pk;
        pk.h2[0] = __float22half2_rn(make_float2(acc.x * 0.25f, acc.y * 0.25f));
        pk.h2[1] = __float22half2_rn(make_float2(acc.z * 0.25f, acc.w * 0.25f));
        *(uint2*)&lds_out[bin * C_ + cb] = pk.u;
    }

    __syncthreads();

    // Copy out with fully-coalesced float4 stores; LDS transpose on the fly.
    float4* o4 = (float4*)(out + (size_t)n * (C_ * PP2));
    for (int i = threadIdx.x; i < (C_ * PP2) / 4; i += 512) {
        const int l0 = i * 4;
        float4 v;
        #pragma unroll
        for (int j = 0; j < 4; ++j) {
            const int l  = l0 + j;
            const int c  = l / PP2;          // magic-mul, constant 49
            const int bn = l - c * PP2;
            ((float*)&v)[j] = __half2float(lds_out[bn * C_ + c]);
        }
        o4[i] = v;
    }
}

// ---------------- Fallback (NCHW direct, fp32) ------------------------------
__global__ __launch_bounds__(256)
void roi_align_kernel(const float* __restrict__ rois,
                      const float* __restrict__ feat,
                      const int* __restrict__ stride_ptr,
                      int B, int C, int H, int W, int N,
                      float* __restrict__ out) {
    const int total = N * C * POOLED * POOLED;
    int idx = blockIdx.x * blockDim.x + threadIdx.x;
    if (idx >= total) return;

    const float scale = 1.0f / (float)stride_ptr[0];

    int pw = idx % POOLED;
    int ph = (idx / POOLED) % POOLED;
    int c  = (idx / (POOLED * POOLED)) % C;
    int n  = idx / (POOLED * POOLED * C);

    const float* r = rois + (size_t)n * 5;
    int b = (int)r[0];
    float x1 = r[1] * scale;
    float y1 = r[2] * scale;
    float x2 = r[3] * scale;
    float y2 = r[4] * scale;
    float bin_w = fmaxf(x2 - x1, 1.0f) / (float)POOLED;
    float bin_h = fmaxf(y2 - y1, 1.0f) / (float)POOLED;

    const float* plane = feat + ((size_t)b * C + c) * (size_t)(H * W);

    float acc = 0.0f;
    #pragma unroll
    for (int sy = 0; sy < RATIO; ++sy) {
        float iy = ((float)(ph * RATIO + sy) + 0.5f) / (float)RATIO;
        float yy = y1 + iy * bin_h;
        bool vy = (yy > -1.0f) && (yy < (float)H);
        float cy = fminf(fmaxf(yy, 0.0f), (float)(H - 1));
        int y0 = (int)floorf(cy);
        if (y0 > H - 1) y0 = H - 1;
        int y1i = min(y0 + 1, H - 1);
        float fy = cy - (float)y0;
        float hy = 1.0f - fy;

        #pragma unroll
        for (int sx = 0; sx < RATIO; ++sx) {
            float ix = ((float)(pw * RATIO + sx) + 0.5f) / (float)RATIO;
            float xx = x1 + ix * bin_w;
            bool vx = (xx > -1.0f) && (xx < (float)W);
            if (!(vy && vx)) continue;
            float cx = fminf(fmaxf(xx, 0.0f), (float)(W - 1));
            int x0 = (int)floorf(cx);
            if (x0 > W - 1) x0 = W - 1;
            int x1i = min(x0 + 1, W - 1);
            float fx = cx - (float)x0;
            float hx = 1.0f - fx;

            float v00 = plane[y0  * W + x0 ];
            float v01 = plane[y0  * W + x1i];
            float v10 = plane[y1i * W + x0 ];
            float v11 = plane[y1i * W + x1i];

            acc += hy * hx * v00 + hy * fx * v01 + fy * hx * v10 + fy * fx * v11;
        }
    }

    out[idx] = acc * 0.25f;
}

extern "C" void kernel_launch(void* const* d_in, const int* in_sizes, int n_in,
                              void* d_out, int out_size, void* d_ws, size_t ws_size,
                              hipStream_t stream) {
    const float* rois = (const float*)d_in[0];
    const float* feat = (const float*)d_in[1];
    const int* stride_ptr = (const int*)d_in[2];

    const int N = in_sizes[0] / 5;
    const int B = in_sizes[1] / (C_ * P_);
    float* out = (float*)d_out;

    const size_t need = (size_t)B * P_ * C_ * sizeof(__half);
    if (ws_size >= need) {
        __half* featT = (__half*)d_ws;
        dim3 tgrid(P_ / TP, C_ / TC, B);
        nchw_to_nhwc_h<<<tgrid, 256, 0, stream>>>(feat, featT);

        roi_align_nhwc_h<<<N, 512, 0, stream>>>(rois, featT, stride_ptr, out, N);
    } else {
        const int total = N * C_ * POOLED * POOLED;
        const int block = 256;
        const int grid = (total + block - 1) / block;
        roi_align_kernel<<<grid, block, 0, stream>>>(rois, feat, stride_ptr,
                                                     B, C_, H_, W_, N, out);
    }
}

// Round 6
// 165.581 us; speedup vs baseline: 1.0208x; 1.0208x over previous
//
#include <hip/hip_runtime.h>
#include <hip/hip_fp16.h>

#define POOLED 7
#define RATIO 2

constexpr int C_ = 256;
constexpr int H_ = 192;
constexpr int W_ = 192;
constexpr int P_ = H_ * W_;           // pixels per plane
constexpr int PP2 = POOLED * POOLED;  // 49

// ---------------- NCHW fp32 -> NHWC fp16 transpose -------------------------
constexpr int TC = 32;
constexpr int TP = 128;
constexpr int TPAD = TP + 1;

__global__ __launch_bounds__(256)
void nchw_to_nhwc_h(const float* __restrict__ in, __half* __restrict__ outT) {
    __shared__ float tile[TC][TPAD];
    const int b  = blockIdx.z;
    const int p0 = blockIdx.x * TP;
    const int c0 = blockIdx.y * TC;
    const float* src = in   + (size_t)b * C_ * P_;
    __half*      dst = outT + (size_t)b * P_ * C_;

    const int t = threadIdx.x;

    #pragma unroll
    for (int k = 0; k < 4; ++k) {
        const int q  = t + 256 * k;
        const int c  = q >> 5;
        const int pv = q & 31;
        const float4 v = *(const float4*)&src[(size_t)(c0 + c) * P_ + p0 + 4 * pv];
        tile[c][4 * pv + 0] = v.x;
        tile[c][4 * pv + 1] = v.y;
        tile[c][4 * pv + 2] = v.z;
        tile[c][4 * pv + 3] = v.w;
    }
    __syncthreads();

    #pragma unroll
    for (int k = 0; k < 2; ++k) {
        const int q  = t + 256 * k;
        const int p  = q >> 2;
        const int c8 = (q & 3) * 8;
        union { __half h[8]; float4 f; } u;
        #pragma unroll
        for (int i = 0; i < 8; ++i) u.h[i] = __float2half(tile[c8 + i][p]);
        *(float4*)&dst[(size_t)(p0 + p) * C_ + c0 + c8] = u.f;
    }
}

// ---------------- RoIAlign on NHWC fp16 ------------------------------------
// Block = 512 (8 waves). LDS ~25.7 KB -> 4 blocks/CU (wave-capped).
// Bin stride padded to 258 halves: epilogue LDS reads conflict-free.
// Coord table: 14 y-samples + 14 x-samples precomputed once per block.
// fp16 pk-fma accumulation; 0.25 mean factor folded into halved fracs.
__global__ __launch_bounds__(512)
void roi_align_nhwc_h(const float* __restrict__ rois,
                      const __half* __restrict__ featT,   // (B,H,W,C) fp16
                      const int* __restrict__ stride_ptr,
                      float* __restrict__ out, int N) {
    constexpr int BSTRIDE = C_ + 2;            // 258 halves
    __shared__ __half lds_out[PP2 * BSTRIDE];  // 25284 B
    __shared__ int4 coord[28];                 // [0..13]=y {lo*W, hi*W, frac*0.5, valid}
                                               // [14..27]=x {lo, hi, frac*0.5, valid}

    const int n    = blockIdx.x;
    const int t    = threadIdx.x;
    const int lane = t & 63;
    const int wave = t >> 6;

    const float scale = 1.0f / (float)stride_ptr[0];
    const float* r = rois + (size_t)n * 5;
    const int   b   = (int)r[0];
    const float rx1 = r[1] * scale;
    const float ry1 = r[2] * scale;
    const float rx2 = r[3] * scale;
    const float ry2 = r[4] * scale;
    const float bin_w = fmaxf(rx2 - rx1, 1.0f) * (1.0f / (float)POOLED);
    const float bin_h = fmaxf(ry2 - ry1, 1.0f) * (1.0f / (float)POOLED);

    if (t < 28) {
        const bool  isY   = t < 14;
        const int   s     = isY ? t : t - 14;
        const float start = isY ? ry1 : rx1;
        const float bsz   = isY ? bin_h : bin_w;
        const int   size  = isY ? H_ : W_;
        const float cc0   = start + ((float)s + 0.5f) * 0.5f * bsz;
        const bool  valid = (cc0 > -1.0f) && (cc0 < (float)size);
        float cc = fminf(fmaxf(cc0, 0.0f), (float)(size - 1));
        int lo = (int)floorf(cc);
        if (lo > size - 1) lo = size - 1;
        const int hi = min(lo + 1, size - 1);
        const float frac = (cc - (float)lo) * 0.5f;   // fold mean/4 (x*y halves)
        int4 e;
        e.x = isY ? lo * W_ : lo;
        e.y = isY ? hi * W_ : hi;
        e.z = __float_as_int(frac);
        e.w = valid ? 1 : 0;
        coord[t] = e;
    }
    __syncthreads();

    const uint2* fbase = (const uint2*)featT + (size_t)b * P_ * (C_ / 4);
    const int cb = lane * 4;

    for (int bin = wave; bin < PP2; bin += 8) {
        const int ph = bin / POOLED;
        const int pw = bin - ph * POOLED;

        const int4 cxA = coord[14 + 2 * pw];
        const int4 cxB = coord[14 + 2 * pw + 1];

        __half2 acc01 = __float2half2_rn(0.f);
        __half2 acc23 = __float2half2_rn(0.f);

        #pragma unroll
        for (int sy = 0; sy < RATIO; ++sy) {
            const int4  cy = coord[2 * ph + sy];
            const float fy = __int_as_float(cy.z);   // frac_y * 0.5
            const float hy = 0.5f - fy;

            #pragma unroll
            for (int sx = 0; sx < RATIO; ++sx) {
                const int4 cx = sx ? cxB : cxA;
                if (!(cy.w & cx.w)) continue;
                const float fx = __int_as_float(cx.z);
                const float hx = 0.5f - fx;

                const __half2 W00 = __float2half2_rn(hy * hx);
                const __half2 W01 = __float2half2_rn(hy * fx);
                const __half2 W10 = __float2half2_rn(fy * hx);
                const __half2 W11 = __float2half2_rn(fy * fx);

                const int p00 = cy.x + cx.x;
                const int p01 = cy.x + cx.y;
                const int p10 = cy.y + cx.x;
                const int p11 = cy.y + cx.y;

                const uint2 r00 = fbase[(size_t)p00 * (C_ / 4) + lane];
                const uint2 r01 = fbase[(size_t)p01 * (C_ / 4) + lane];
                const uint2 r10 = fbase[(size_t)p10 * (C_ / 4) + lane];
                const uint2 r11 = fbase[(size_t)p11 * (C_ / 4) + lane];

                acc01 = __hfma2(W00, *(const __half2*)&r00.x, acc01);
                acc23 = __hfma2(W00, *(const __half2*)&r00.y, acc23);
                acc01 = __hfma2(W01, *(const __half2*)&r01.x, acc01);
                acc23 = __hfma2(W01, *(const __half2*)&r01.y, acc23);
                acc01 = __hfma2(W10, *(const __half2*)&r10.x, acc01);
                acc23 = __hfma2(W10, *(const __half2*)&r10.y, acc23);
                acc01 = __hfma2(W11, *(const __half2*)&r11.x, acc01);
                acc23 = __hfma2(W11, *(const __half2*)&r11.y, acc23);
            }
        }

        __half2* dst = (__half2*)&lds_out[bin * BSTRIDE + cb];  // 4-B aligned
        dst[0] = acc01;
        dst[1] = acc23;
    }

    __syncthreads();

    // Coalesced float4 stores; conflict-free strided LDS reads (stride 258h).
    float4* o4 = (float4*)(out + (size_t)n * (C_ * PP2));
    for (int i = t; i < (C_ * PP2) / 4; i += 512) {
        const int l0 = i * 4;
        float4 v;
        #pragma unroll
        for (int j = 0; j < 4; ++j) {
            const int l  = l0 + j;
            const int c  = l / PP2;
            const int bn = l - c * PP2;
            ((float*)&v)[j] = __half2float(lds_out[bn * BSTRIDE + c]);
        }
        o4[i] = v;
    }
}

// ---------------- Fallback (NCHW direct, fp32) ------------------------------
__global__ __launch_bounds__(256)
void roi_align_kernel(const float* __restrict__ rois,
                      const float* __restrict__ feat,
                      const int* __restrict__ stride_ptr,
                      int B, int C, int H, int W, int N,
                      float* __restrict__ out) {
    const int total = N * C * POOLED * POOLED;
    int idx = blockIdx.x * blockDim.x + threadIdx.x;
    if (idx >= total) return;

    const float scale = 1.0f / (float)stride_ptr[0];

    int pw = idx % POOLED;
    int ph = (idx / POOLED) % POOLED;
    int c  = (idx / (POOLED * POOLED)) % C;
    int n  = idx / (POOLED * POOLED * C);

    const float* r = rois + (size_t)n * 5;
    int b = (int)r[0];
    float x1 = r[1] * scale;
    float y1 = r[2] * scale;
    float x2 = r[3] * scale;
    float y2 = r[4] * scale;
    float bin_w = fmaxf(x2 - x1, 1.0f) / (float)POOLED;
    float bin_h = fmaxf(y2 - y1, 1.0f) / (float)POOLED;

    const float* plane = feat + ((size_t)b * C + c) * (size_t)(H * W);

    float acc = 0.0f;
    #pragma unroll
    for (int sy = 0; sy < RATIO; ++sy) {
        float iy = ((float)(ph * RATIO + sy) + 0.5f) / (float)RATIO;
        float yy = y1 + iy * bin_h;
        bool vy = (yy > -1.0f) && (yy < (float)H);
        float cy = fminf(fmaxf(yy, 0.0f), (float)(H - 1));
        int y0 = (int)floorf(cy);
        if (y0 > H - 1) y0 = H - 1;
        int y1i = min(y0 + 1, H - 1);
        float fy = cy - (float)y0;
        float hy = 1.0f - fy;

        #pragma unroll
        for (int sx = 0; sx < RATIO; ++sx) {
            float ix = ((float)(pw * RATIO + sx) + 0.5f) / (float)RATIO;
            float xx = x1 + ix * bin_w;
            bool vx = (xx > -1.0f) && (xx < (float)W);
            if (!(vy && vx)) continue;
            float cx = fminf(fmaxf(xx, 0.0f), (float)(W - 1));
            int x0 = (int)floorf(cx);
            if (x0 > W - 1) x0 = W - 1;
            int x1i = min(x0 + 1, W - 1);
            float fx = cx - (float)x0;
            float hx = 1.0f - fx;

            float v00 = plane[y0  * W + x0 ];
            float v01 = plane[y0  * W + x1i];
            float v10 = plane[y1i * W + x0 ];
            float v11 = plane[y1i * W + x1i];

            acc += hy * hx * v00 + hy * fx * v01 + fy * hx * v10 + fy * fx * v11;
        }
    }

    out[idx] = acc * 0.25f;
}

extern "C" void kernel_launch(void* const* d_in, const int* in_sizes, int n_in,
                              void* d_out, int out_size, void* d_ws, size_t ws_size,
                              hipStream_t stream) {
    const float* rois = (const float*)d_in[0];
    const float* feat = (const float*)d_in[1];
    const int* stride_ptr = (const int*)d_in[2];

    const int N = in_sizes[0] / 5;
    const int B = in_sizes[1] / (C_ * P_);
    float* out = (float*)d_out;

    const size_t need = (size_t)B * P_ * C_ * sizeof(__half);
    if (ws_size >= need) {
        __half* featT = (__half*)d_ws;
        dim3 tgrid(P_ / TP, C_ / TC, B);
        nchw_to_nhwc_h<<<tgrid, 256, 0, stream>>>(feat, featT);

        roi_align_nhwc_h<<<N, 512, 0, stream>>>(rois, featT, stride_ptr, out, N);
    } else {
        const int total = N * C_ * POOLED * POOLED;
        const int block = 256;
        const int grid = (total + block - 1) / block;
        roi_align_kernel<<<grid, block, 0, stream>>>(rois, feat, stride_ptr,
                                                     B, C_, H_, W_, N, out);
    }
}